// Round 1
// baseline (13072.421 us; speedup 1.0000x reference)
//
#include <hip/hip_runtime.h>
#include <math.h>

#define B_   8
#define C_   256
#define NH_  8
#define DK_  32
#define DV_  32
#define N_   1024
#define EPS_ 1e-6f
#define INV_TEMP 0.17677669529663687f   /* 1/sqrt(32) */
#define INV_PI   0.3183098861837907f

__device__ __forceinline__ float mishf(float x) {
    float sp = (x > 20.f) ? x : log1pf(expf(x));
    return x * tanhf(sp);
}

// ---------------- Kernel 1: q,k,v grouped conv + BN affine + mish ----------
__global__ __launch_bounds__(256) void qkv_kernel(
    const float* __restrict__ x,
    const float* __restrict__ qw, const float* __restrict__ qb2,
    const float* __restrict__ qs, const float* __restrict__ qbeta,
    const float* __restrict__ kw, const float* __restrict__ kb2,
    const float* __restrict__ ks, const float* __restrict__ kbeta,
    const float* __restrict__ vw, const float* __restrict__ vb2,
    const float* __restrict__ vs, const float* __restrict__ vbeta,
    float* __restrict__ q, float* __restrict__ k, float* __restrict__ v)
{
    int id = blockIdx.x * 256 + threadIdx.x;     // (b, co, n)
    int n  = id & (N_ - 1);
    int co = (id >> 10) & 255;
    int b  = id >> 18;
    int g  = co >> 5;                            // group (= head)
    const float* xp = x + ((size_t)b * C_ + g * 32) * N_ + n;
    float accq = 0.f, acck = 0.f, accv = 0.f;
#pragma unroll
    for (int i = 0; i < 32; ++i) {
        float xv = xp[(size_t)i * N_];
        accq = fmaf(xv, qw[co * 32 + i], accq);
        acck = fmaf(xv, kw[co * 32 + i], acck);
        accv = fmaf(xv, vw[co * 32 + i], accv);
    }
    float yq = mishf(qs[co] * (accq + qb2[co]) + qbeta[co]) * INV_TEMP;
    float yk = mishf(ks[co] * (acck + kb2[co]) + kbeta[co]);
    float yv = mishf(vs[co] * (accv + vb2[co]) + vbeta[co]);
    q[id] = yq; k[id] = yk; v[id] = yv;
}

// ---------------- Kernel 1b: row norms of q and k ---------------------------
__global__ __launch_bounds__(256) void norm_kernel(
    const float* __restrict__ q, const float* __restrict__ k,
    float* __restrict__ qn, float* __restrict__ kn)
{
    int id = blockIdx.x * 256 + threadIdx.x;     // (bh, n)
    int n  = id & (N_ - 1);
    int bh = id >> 10;
    const float* qp = q + (size_t)bh * 32 * N_ + n;
    const float* kp = k + (size_t)bh * 32 * N_ + n;
    float sq = 0.f, sk = 0.f;
#pragma unroll
    for (int d = 0; d < 32; ++d) {
        float a = qp[(size_t)d * N_]; sq = fmaf(a, a, sq);
        float c = kp[(size_t)d * N_]; sk = fmaf(c, c, sk);
    }
    qn[id] = sqrtf(sq);
    kn[id] = sqrtf(sk);
}

// ---------------- Kernel 2: attention -------------------------------------
// One block (4 waves) per (b, h, 16-row tile). Wave w handles rows
// itile*16 + w*4 + r, r=0..3.  Lane l owns keys m = l + 64*j, j=0..15.
__global__ __launch_bounds__(256) void attn_kernel(
    const float* __restrict__ q, const float* __restrict__ k,
    const float* __restrict__ v, const float* __restrict__ qn,
    const float* __restrict__ kn, float* __restrict__ aout,
    float* __restrict__ ampart)
{
    __shared__ float amW[4][N_];
    int tid  = threadIdx.x;
    int wave = tid >> 6, lane = tid & 63;
    int blk   = blockIdx.x;                 // bh*64 + itile
    int itile = blk & 63;
    int bh    = blk >> 6;
    const float* qb  = q  + (size_t)bh * 32 * N_;
    const float* kb  = k  + (size_t)bh * 32 * N_;
    const float* vb  = v  + (size_t)bh * 32 * N_;
    const float* qnb = qn + (size_t)bh * N_;
    const float* knb = kn + (size_t)bh * N_;

    for (int m = tid; m < 4 * N_; m += 256) (&amW[0][0])[m] = 0.f;
    __syncthreads();

    float knr[16];
#pragma unroll
    for (int j = 0; j < 16; ++j) knr[j] = knb[lane + 64 * j];

    for (int r = 0; r < 4; ++r) {
        int i = itile * 16 + wave * 4 + r;
        float qreg[32];
#pragma unroll
        for (int d = 0; d < 32; ++d) qreg[d] = qb[(size_t)d * N_ + i];
        float qni = qnb[i];
        float e[16];
        float o[32];
#pragma unroll
        for (int d = 0; d < 32; ++d) o[d] = 0.f;
        float ssum = 0.f;
#pragma unroll
        for (int j = 0; j < 16; ++j) {
            int m = lane + 64 * j;
            float dot = 0.f;
#pragma unroll
            for (int d = 0; d < 32; ++d)
                dot = fmaf(qreg[d], kb[(size_t)d * N_ + m], dot);
            float denom = fmaxf(qni * knr[j], EPS_);
            float c = dot / denom;
            c = fminf(fmaxf(c, -1.f + 1e-6f), 1.f - 1e-6f);
            float logit = 1.f - acosf(c) * INV_PI;
            float ee = expf(logit);
            e[j] = ee;
            ssum += ee;
#pragma unroll
            for (int d = 0; d < 32; ++d)
                o[d] = fmaf(ee, vb[(size_t)d * N_ + m], o[d]);
        }
        // wave-reduce softmax denominator
#pragma unroll
        for (int off = 32; off >= 1; off >>= 1)
            ssum += __shfl_xor(ssum, off, 64);
        float inv = 1.f / ssum;
        // attention-map partial accumulation (lanes own distinct m -> no race)
#pragma unroll
        for (int j = 0; j < 16; ++j)
            amW[wave][lane + 64 * j] += e[j] * inv;
        // reduce o[] across the wave; lane d keeps element d
        float mine = 0.f;
#pragma unroll
        for (int d = 0; d < 32; ++d) {
            float s = o[d];
#pragma unroll
            for (int off = 32; off >= 1; off >>= 1)
                s += __shfl_xor(s, off, 64);
            if (lane == d) mine = s;
        }
        if (lane < 32)
            aout[((size_t)bh * 32 + lane) * N_ + i] = mine * inv;
    }
    __syncthreads();
    for (int m = tid; m < N_; m += 256)
        ampart[(size_t)blk * N_ + m] =
            (amW[0][m] + amW[1][m] + amW[2][m] + amW[3][m]) * (1.f / NH_);
}

// ---------------- Kernel 3: attention-map reduce + min/max normalize -------
__global__ __launch_bounds__(256) void am_kernel(
    const float* __restrict__ amp, float* __restrict__ outAm)
{
    int b = blockIdx.x, tid = threadIdx.x;
    float s[4] = {0.f, 0.f, 0.f, 0.f};
    const float* base = amp + (size_t)b * 512 * N_;
    for (int p = 0; p < 512; ++p) {
#pragma unroll
        for (int c2 = 0; c2 < 4; ++c2)
            s[c2] += base[(size_t)p * N_ + tid + 256 * c2];
    }
    float mn = fminf(fminf(s[0], s[1]), fminf(s[2], s[3]));
    float mx = fmaxf(fmaxf(s[0], s[1]), fmaxf(s[2], s[3]));
    __shared__ float rmn[256], rmx[256];
    rmn[tid] = mn; rmx[tid] = mx;
    __syncthreads();
    for (int off = 128; off >= 1; off >>= 1) {
        if (tid < off) {
            rmn[tid] = fminf(rmn[tid], rmn[tid + off]);
            rmx[tid] = fmaxf(rmx[tid], rmx[tid + off]);
        }
        __syncthreads();
    }
    mn = rmn[0]; mx = rmx[0];
    float inv = 1.f / (mx - mn);
#pragma unroll
    for (int c2 = 0; c2 < 4; ++c2)
        outAm[(size_t)b * N_ + tid + 256 * c2] = (s[c2] - mn) * inv;
}

// ---------------- Kernel 4: final 1x1 conv + mish + residual ---------------
__global__ __launch_bounds__(256) void fconv_kernel(
    const float* __restrict__ aout, const float* __restrict__ x,
    const float* __restrict__ fw, const float* __restrict__ fb,
    const float* __restrict__ fs, const float* __restrict__ fbeta,
    float* __restrict__ y)
{
    int id = blockIdx.x * 256 + threadIdx.x;     // (b, co, n)
    int n  = id & (N_ - 1);
    int co = (id >> 10) & 255;
    int b  = id >> 18;
    const float* ap = aout + (size_t)b * C_ * N_ + n;
    const float* wp = fw + co * C_;
    float acc = 0.f;
#pragma unroll 8
    for (int ci = 0; ci < 256; ++ci)
        acc = fmaf(ap[(size_t)ci * N_], wp[ci], acc);
    y[id] = mishf(fs[co] * (acc + fb[co]) + fbeta[co]) + x[id];
}

extern "C" void kernel_launch(void* const* d_in, const int* in_sizes, int n_in,
                              void* d_out, int out_size, void* d_ws, size_t ws_size,
                              hipStream_t stream)
{
    const float* x     = (const float*)d_in[0];
    const float* q_w   = (const float*)d_in[1];
    const float* q_b   = (const float*)d_in[2];
    const float* q_s   = (const float*)d_in[3];
    const float* q_be  = (const float*)d_in[4];
    const float* k_w   = (const float*)d_in[5];
    const float* k_b   = (const float*)d_in[6];
    const float* k_s   = (const float*)d_in[7];
    const float* k_be  = (const float*)d_in[8];
    const float* v_w   = (const float*)d_in[9];
    const float* v_b   = (const float*)d_in[10];
    const float* v_s   = (const float*)d_in[11];
    const float* v_be  = (const float*)d_in[12];
    const float* f_w   = (const float*)d_in[13];
    const float* f_b   = (const float*)d_in[14];
    const float* f_s   = (const float*)d_in[15];
    const float* f_be  = (const float*)d_in[16];

    float* y_out  = (float*)d_out;                      // (8,256,32,32)
    float* am_out = (float*)d_out + (size_t)B_ * C_ * N_; // (8,32,32)

    float* ws   = (float*)d_ws;
    float* q    = ws;                                   // 2M floats
    float* k    = q   + (size_t)B_ * C_ * N_;
    float* v    = k   + (size_t)B_ * C_ * N_;
    float* qn   = v   + (size_t)B_ * C_ * N_;           // 64K
    float* kn   = qn  + (size_t)B_ * NH_ * N_;          // 64K
    float* aout = kn  + (size_t)B_ * NH_ * N_;          // 2M
    float* amp  = aout + (size_t)B_ * C_ * N_;          // 4096*1024

    qkv_kernel<<<(B_ * C_ * N_) / 256, 256, 0, stream>>>(
        x, q_w, q_b, q_s, q_be, k_w, k_b, k_s, k_be,
        v_w, v_b, v_s, v_be, q, k, v);

    norm_kernel<<<(B_ * NH_ * N_) / 256, 256, 0, stream>>>(q, k, qn, kn);

    attn_kernel<<<B_ * NH_ * 64, 256, 0, stream>>>(q, k, v, qn, kn, aout, amp);

    am_kernel<<<B_, 256, 0, stream>>>(amp, am_out);

    fconv_kernel<<<(B_ * C_ * N_) / 256, 256, 0, stream>>>(
        aout, x, f_w, f_b, f_s, f_be, y_out);
}

// Round 2
// 566.742 us; speedup vs baseline: 23.0659x; 23.0659x over previous
//
#include <hip/hip_runtime.h>
#include <math.h>

#define B_   8
#define C_   256
#define NH_  8
#define N_   1024
#define EPS_ 1e-6f
#define INV_TEMP 0.17677669529663687f   /* 1/sqrt(32) */
#define INV_PI   0.3183098861837907f
#define LOG2E    1.4426950408889634f
#define CLAMP_   0.999999f              /* 1 - 1e-6 */

__device__ __forceinline__ float mishf(float x) {
    float sp = (x > 20.f) ? x : log1pf(expf(x));
    return x * tanhf(sp);
}

// Hastings acos approx, abs err ~6.8e-5 rad (logit err ~2e-5, well under tol)
__device__ __forceinline__ float fast_acosf(float c) {
    float a = fabsf(c);
    float p = -0.0187293f;
    p = fmaf(p, a, 0.0742610f);
    p = fmaf(p, a, -0.2121144f);
    p = fmaf(p, a, 1.5707288f);
    float r = p * sqrtf(1.0f - a);
    return (c < 0.0f) ? (3.14159265358979f - r) : r;
}

__device__ __forceinline__ unsigned bf16r(float x) {   // RNE f32->bf16 bits
    unsigned b = __float_as_uint(x);
    return (b + 0x7fffu + ((b >> 16) & 1u)) >> 16;
}

// ---------------- Kernel 1: q,k,v grouped conv + BN affine + mish ----------
__global__ __launch_bounds__(256) void qkv_kernel(
    const float* __restrict__ x,
    const float* __restrict__ qw, const float* __restrict__ qb2,
    const float* __restrict__ qs, const float* __restrict__ qbeta,
    const float* __restrict__ kw, const float* __restrict__ kb2,
    const float* __restrict__ ks, const float* __restrict__ kbeta,
    const float* __restrict__ vw, const float* __restrict__ vb2,
    const float* __restrict__ vs, const float* __restrict__ vbeta,
    float* __restrict__ q, float* __restrict__ k, float* __restrict__ v)
{
    int id = blockIdx.x * 256 + threadIdx.x;     // (b, co, n)
    int n  = id & (N_ - 1);
    int co = (id >> 10) & 255;
    int b  = id >> 18;
    int g  = co >> 5;
    const float* xp = x + ((size_t)b * C_ + g * 32) * N_ + n;
    float accq = 0.f, acck = 0.f, accv = 0.f;
#pragma unroll
    for (int i = 0; i < 32; ++i) {
        float xv = xp[(size_t)i * N_];
        accq = fmaf(xv, qw[co * 32 + i], accq);
        acck = fmaf(xv, kw[co * 32 + i], acck);
        accv = fmaf(xv, vw[co * 32 + i], accv);
    }
    float yq = mishf(qs[co] * (accq + qb2[co]) + qbeta[co]) * INV_TEMP;
    float yk = mishf(ks[co] * (acck + kb2[co]) + kbeta[co]);
    float yv = mishf(vs[co] * (accv + vb2[co]) + vbeta[co]);
    q[id] = yq; k[id] = yk; v[id] = yv;
}

// ---------------- Kernel 1b: row norms of q and k ---------------------------
__global__ __launch_bounds__(256) void norm_kernel(
    const float* __restrict__ q, const float* __restrict__ k,
    float* __restrict__ qn, float* __restrict__ kn)
{
    int id = blockIdx.x * 256 + threadIdx.x;     // (bh, n)
    int n  = id & (N_ - 1);
    int bh = id >> 10;
    const float* qp = q + (size_t)bh * 32 * N_ + n;
    const float* kp = k + (size_t)bh * 32 * N_ + n;
    float sq = 0.f, sk = 0.f;
#pragma unroll
    for (int d = 0; d < 32; ++d) {
        float a = qp[(size_t)d * N_]; sq = fmaf(a, a, sq);
        float c = kp[(size_t)d * N_]; sk = fmaf(c, c, sk);
    }
    qn[id] = sqrtf(sq);
    kn[id] = sqrtf(sk);
}

// ---------------- Kernel 2: attention (LDS-tiled, two-sweep) ----------------
// Block: 256 threads, one (b,h) x 64-row tile. m swept in 8 chunks of 128.
// Sweep 1: dots + transcendental -> row sums (no max-subtract: logits in (0,1)).
// Sweep 2: recompute, normalize, P->bf16 LDS tile, PV accumulate, am colsums.
__global__ __launch_bounds__(256) void attn_kernel(
    const float* __restrict__ q, const float* __restrict__ k,
    const float* __restrict__ v, const float* __restrict__ qn,
    const float* __restrict__ kn, float* __restrict__ aout,
    float* __restrict__ ampart)
{
    __shared__ __align__(16) float qs[32][64];        // 8 KB  [d][i]
    __shared__ __align__(16) float ks[32][128];       // 16 KB [d][m]
    __shared__ __align__(16) float vsm[128][32];      // 16 KB [m][d] xor-swz
    __shared__ __align__(16) unsigned int pT[128*32]; // 16 KB [m][i] bf16 swz
    __shared__ __align__(16) float amW[N_];           // 4 KB
    __shared__ __align__(16) float knl[128];

    int tid = threadIdx.x;
    int blk = blockIdx.x;
    int itile = blk & 15;
    int bh    = blk >> 4;
    int i0    = itile * 64;
    const float* qb = q + (size_t)bh * 32 * N_;
    const float* kb = k + (size_t)bh * 32 * N_;
    const float* vb = v + (size_t)bh * 32 * N_;

    int ty = tid >> 5, tx = tid & 31;   // phase A: rows ty*8..+8, cols tx*4..+4

    // stage qs + zero amW (covered by first loop barrier)
    {
        int d = tid >> 3, ii = (tid & 7) * 8;
        float4 a0 = *(const float4*)&qb[(size_t)d * N_ + i0 + ii];
        float4 a1 = *(const float4*)&qb[(size_t)d * N_ + i0 + ii + 4];
        *(float4*)&qs[d][ii]     = a0;
        *(float4*)&qs[d][ii + 4] = a1;
        for (int j = tid; j < N_; j += 256) amW[j] = 0.f;
    }
    float qnr[8];
#pragma unroll
    for (int rr = 0; rr < 8; ++rr)
        qnr[rr] = qn[(size_t)bh * N_ + i0 + ty * 8 + rr];

    float rs[8];
#pragma unroll
    for (int rr = 0; rr < 8; ++rr) rs[rr] = 0.f;

    // ---------------- sweep 1: row sums ----------------
    for (int ch = 0; ch < 8; ++ch) {
        int m0 = ch * 128;
        __syncthreads();
        {   // stage ks + knl
            int d = tid >> 3, mb = (tid & 7) * 16;
#pragma unroll
            for (int j = 0; j < 16; j += 4)
                *(float4*)&ks[d][mb + j] =
                    *(const float4*)&kb[(size_t)d * N_ + m0 + mb + j];
            if (tid < 128) knl[tid] = kn[(size_t)bh * N_ + m0 + tid];
        }
        __syncthreads();

        float acc[8][4];
#pragma unroll
        for (int rr = 0; rr < 8; ++rr)
#pragma unroll
            for (int mm = 0; mm < 4; ++mm) acc[rr][mm] = 0.f;
#pragma unroll
        for (int d = 0; d < 32; ++d) {
            float4 qa = *(const float4*)&qs[d][ty * 8];
            float4 qc = *(const float4*)&qs[d][ty * 8 + 4];
            float4 kv = *(const float4*)&ks[d][tx * 4];
            float qv[8] = {qa.x, qa.y, qa.z, qa.w, qc.x, qc.y, qc.z, qc.w};
            float kl[4] = {kv.x, kv.y, kv.z, kv.w};
#pragma unroll
            for (int rr = 0; rr < 8; ++rr)
#pragma unroll
                for (int mm = 0; mm < 4; ++mm)
                    acc[rr][mm] = fmaf(qv[rr], kl[mm], acc[rr][mm]);
        }
        float4 kncv = *(const float4*)&knl[tx * 4];
        float knc[4] = {kncv.x, kncv.y, kncv.z, kncv.w};
#pragma unroll
        for (int rr = 0; rr < 8; ++rr) {
            float psum = 0.f;
#pragma unroll
            for (int mm = 0; mm < 4; ++mm) {
                float den = fmaxf(qnr[rr] * knc[mm], EPS_);
                float c = acc[rr][mm] * __builtin_amdgcn_rcpf(den);
                c = __builtin_amdgcn_fmed3f(c, -CLAMP_, CLAMP_);
                float lg = 1.0f - fast_acosf(c) * INV_PI;
                psum += exp2f(lg * LOG2E);
            }
            rs[rr] += psum;
        }
    }
    // reduce rs across the 32-lane group sharing these rows
#pragma unroll
    for (int rr = 0; rr < 8; ++rr) {
#pragma unroll
        for (int off = 16; off >= 1; off >>= 1)
            rs[rr] += __shfl_xor(rs[rr], off, 64);
    }
    float rinv[8];
#pragma unroll
    for (int rr = 0; rr < 8; ++rr) rinv[rr] = __builtin_amdgcn_rcpf(rs[rr]);

    // ---------------- sweep 2: PV + attention map ----------------
    float o[8];
#pragma unroll
    for (int rr = 0; rr < 8; ++rr) o[rr] = 0.f;

    for (int ch = 0; ch < 8; ++ch) {
        int m0 = ch * 128;
        __syncthreads();
        {   // stage ks + knl + vsm (transposed, xor-swizzled)
            int d = tid >> 3, mb = (tid & 7) * 16;
#pragma unroll
            for (int j = 0; j < 16; j += 4)
                *(float4*)&ks[d][mb + j] =
                    *(const float4*)&kb[(size_t)d * N_ + m0 + mb + j];
            if (tid < 128) knl[tid] = kn[(size_t)bh * N_ + m0 + tid];
            int vcol = d ^ ((tid & 7) << 2);   // key = (m>>4)&7 = tid&7
#pragma unroll
            for (int j = 0; j < 16; j += 4) {
                float4 vv = *(const float4*)&vb[(size_t)d * N_ + m0 + mb + j];
                vsm[mb + j + 0][vcol] = vv.x;
                vsm[mb + j + 1][vcol] = vv.y;
                vsm[mb + j + 2][vcol] = vv.z;
                vsm[mb + j + 3][vcol] = vv.w;
            }
        }
        __syncthreads();

        // phase A: recompute e, normalize, am colsums, pT write
        float acc[8][4];
#pragma unroll
        for (int rr = 0; rr < 8; ++rr)
#pragma unroll
            for (int mm = 0; mm < 4; ++mm) acc[rr][mm] = 0.f;
#pragma unroll
        for (int d = 0; d < 32; ++d) {
            float4 qa = *(const float4*)&qs[d][ty * 8];
            float4 qc = *(const float4*)&qs[d][ty * 8 + 4];
            float4 kv = *(const float4*)&ks[d][tx * 4];
            float qv[8] = {qa.x, qa.y, qa.z, qa.w, qc.x, qc.y, qc.z, qc.w};
            float kl[4] = {kv.x, kv.y, kv.z, kv.w};
#pragma unroll
            for (int rr = 0; rr < 8; ++rr)
#pragma unroll
                for (int mm = 0; mm < 4; ++mm)
                    acc[rr][mm] = fmaf(qv[rr], kl[mm], acc[rr][mm]);
        }
        float4 kncv = *(const float4*)&knl[tx * 4];
        float knc[4] = {kncv.x, kncv.y, kncv.z, kncv.w};
        float p[8][4];
#pragma unroll
        for (int rr = 0; rr < 8; ++rr)
#pragma unroll
            for (int mm = 0; mm < 4; ++mm) {
                float den = fmaxf(qnr[rr] * knc[mm], EPS_);
                float c = acc[rr][mm] * __builtin_amdgcn_rcpf(den);
                c = __builtin_amdgcn_fmed3f(c, -CLAMP_, CLAMP_);
                float lg = 1.0f - fast_acosf(c) * INV_PI;
                p[rr][mm] = exp2f(lg * LOG2E) * rinv[rr];
            }
        // attention-map column sums (normalized)
#pragma unroll
        for (int mm = 0; mm < 4; ++mm) {
            float s = 0.f;
#pragma unroll
            for (int rr = 0; rr < 8; ++rr) s += p[rr][mm];
            atomicAdd(&amW[m0 + tx * 4 + mm], s);
        }
        // pT write: [m][i] bf16 pairs, 16B-granule xor swizzle, key=(m>>2)&7=tx&7
        {
            int key = (tx & 7) << 4;
#pragma unroll
            for (int mm = 0; mm < 4; ++mm) {
                int m = tx * 4 + mm;
#pragma unroll
                for (int c2 = 0; c2 < 4; ++c2) {
                    unsigned w = bf16r(p[2 * c2][mm]) |
                                 (bf16r(p[2 * c2 + 1][mm]) << 16);
                    int byteoff = (ty * 16 + c2 * 4) ^ key;
                    pT[m * 32 + (byteoff >> 2)] = w;
                }
            }
        }
        __syncthreads();

        // phase B: PV accumulate. thread = (d=tx, rows ty*8..+8)
        {
            int dd = tx, ii = ty;
#pragma unroll 4
            for (int m = 0; m < 128; ++m) {
                float vv = vsm[m][dd ^ (((m >> 4) & 7) << 2)];
                const uint4 pw = *(const uint4*)((const char*)pT + m * 128 +
                                  ((ii * 16) ^ (((m >> 2) & 7) << 4)));
                o[0] = fmaf(__uint_as_float(pw.x << 16),        vv, o[0]);
                o[1] = fmaf(__uint_as_float(pw.x & 0xffff0000u), vv, o[1]);
                o[2] = fmaf(__uint_as_float(pw.y << 16),        vv, o[2]);
                o[3] = fmaf(__uint_as_float(pw.y & 0xffff0000u), vv, o[3]);
                o[4] = fmaf(__uint_as_float(pw.z << 16),        vv, o[4]);
                o[5] = fmaf(__uint_as_float(pw.z & 0xffff0000u), vv, o[5]);
                o[6] = fmaf(__uint_as_float(pw.w << 16),        vv, o[6]);
                o[7] = fmaf(__uint_as_float(pw.w & 0xffff0000u), vv, o[7]);
            }
        }
    }
    __syncthreads();

    // epilogue: transpose o through LDS (reuse pT space) for coalesced writes
    {
        float* oT = (float*)pT;                 // [32 d][64 i], xor-swizzled
        int key = (tx & 7) << 4;
#pragma unroll
        for (int rr = 0; rr < 8; ++rr) {
            int i = ty * 8 + rr;
            int byteoff = (i * 4) ^ key;
            oT[tx * 64 + (byteoff >> 2)] = o[rr];
        }
    }
    __syncthreads();
    {
        const float* oT = (const float*)pT;
        int d = tid >> 3, ii2 = (tid & 7) * 8;
        int key = (d & 7) << 4;
        float4 r0 = *(const float4*)((const char*)oT + d * 256 + ((ii2 * 4) ^ key));
        float4 r1 = *(const float4*)((const char*)oT + d * 256 + (((ii2 + 4) * 4) ^ key));
        *(float4*)&aout[((size_t)bh * 32 + d) * N_ + i0 + ii2]     = r0;
        *(float4*)&aout[((size_t)bh * 32 + d) * N_ + i0 + ii2 + 4] = r1;
    }
    for (int j = tid; j < N_; j += 256)
        ampart[(size_t)blk * N_ + j] = amW[j];
}

// ---------------- Kernel 3: attention-map reduce + min/max normalize -------
__global__ __launch_bounds__(256) void am_kernel(
    const float* __restrict__ amp, float* __restrict__ outAm)
{
    int b = blockIdx.x, tid = threadIdx.x;
    float s[4] = {0.f, 0.f, 0.f, 0.f};
    const float* base = amp + (size_t)b * 128 * N_;
    for (int p = 0; p < 128; ++p) {
#pragma unroll
        for (int c2 = 0; c2 < 4; ++c2)
            s[c2] += base[(size_t)p * N_ + tid + 256 * c2];
    }
    // min/max normalize is scale-invariant -> skip the 1/NH factor
    float mn = fminf(fminf(s[0], s[1]), fminf(s[2], s[3]));
    float mx = fmaxf(fmaxf(s[0], s[1]), fmaxf(s[2], s[3]));
    __shared__ float rmn[256], rmx[256];
    rmn[tid] = mn; rmx[tid] = mx;
    __syncthreads();
    for (int off = 128; off >= 1; off >>= 1) {
        if (tid < off) {
            rmn[tid] = fminf(rmn[tid], rmn[tid + off]);
            rmx[tid] = fmaxf(rmx[tid], rmx[tid + off]);
        }
        __syncthreads();
    }
    mn = rmn[0]; mx = rmx[0];
    float inv = 1.f / (mx - mn);
#pragma unroll
    for (int c2 = 0; c2 < 4; ++c2)
        outAm[(size_t)b * N_ + tid + 256 * c2] = (s[c2] - mn) * inv;
}

// ---------------- Kernel 4: final 1x1 conv + mish + residual ---------------
__global__ __launch_bounds__(256) void fconv_kernel(
    const float* __restrict__ aout, const float* __restrict__ x,
    const float* __restrict__ fw, const float* __restrict__ fb,
    const float* __restrict__ fs, const float* __restrict__ fbeta,
    float* __restrict__ y)
{
    int id = blockIdx.x * 256 + threadIdx.x;     // (b, co, n)
    int n  = id & (N_ - 1);
    int co = (id >> 10) & 255;
    int b  = id >> 18;
    const float* ap = aout + (size_t)b * C_ * N_ + n;
    const float* wp = fw + co * C_;
    float acc = 0.f;
#pragma unroll 8
    for (int ci = 0; ci < 256; ++ci)
        acc = fmaf(ap[(size_t)ci * N_], wp[ci], acc);
    y[id] = mishf(fs[co] * (acc + fb[co]) + fbeta[co]) + x[id];
}

extern "C" void kernel_launch(void* const* d_in, const int* in_sizes, int n_in,
                              void* d_out, int out_size, void* d_ws, size_t ws_size,
                              hipStream_t stream)
{
    const float* x     = (const float*)d_in[0];
    const float* q_w   = (const float*)d_in[1];
    const float* q_b   = (const float*)d_in[2];
    const float* q_s   = (const float*)d_in[3];
    const float* q_be  = (const float*)d_in[4];
    const float* k_w   = (const float*)d_in[5];
    const float* k_b   = (const float*)d_in[6];
    const float* k_s   = (const float*)d_in[7];
    const float* k_be  = (const float*)d_in[8];
    const float* v_w   = (const float*)d_in[9];
    const float* v_b   = (const float*)d_in[10];
    const float* v_s   = (const float*)d_in[11];
    const float* v_be  = (const float*)d_in[12];
    const float* f_w   = (const float*)d_in[13];
    const float* f_b   = (const float*)d_in[14];
    const float* f_s   = (const float*)d_in[15];
    const float* f_be  = (const float*)d_in[16];

    float* y_out  = (float*)d_out;                        // (8,256,32,32)
    float* am_out = (float*)d_out + (size_t)B_ * C_ * N_; // (8,32,32)

    float* ws   = (float*)d_ws;
    float* q    = ws;
    float* k    = q   + (size_t)B_ * C_ * N_;
    float* v    = k   + (size_t)B_ * C_ * N_;
    float* qn   = v   + (size_t)B_ * C_ * N_;
    float* kn   = qn  + (size_t)B_ * NH_ * N_;
    float* aout = kn  + (size_t)B_ * NH_ * N_;
    float* amp  = aout + (size_t)B_ * C_ * N_;            // 1024*1024 floats

    qkv_kernel<<<(B_ * C_ * N_) / 256, 256, 0, stream>>>(
        x, q_w, q_b, q_s, q_be, k_w, k_b, k_s, k_be,
        v_w, v_b, v_s, v_be, q, k, v);

    norm_kernel<<<(B_ * NH_ * N_) / 256, 256, 0, stream>>>(q, k, qn, kn);

    attn_kernel<<<B_ * NH_ * 16, 256, 0, stream>>>(q, k, v, qn, kn, aout, amp);

    am_kernel<<<B_, 256, 0, stream>>>(amp, am_out);

    fconv_kernel<<<(B_ * C_ * N_) / 256, 256, 0, stream>>>(
        aout, x, f_w, f_b, f_s, f_be, y_out);
}

// Round 3
// 298.077 us; speedup vs baseline: 43.8559x; 1.9013x over previous
//
#include <hip/hip_runtime.h>
#include <math.h>

#define B_   8
#define C_   256
#define NH_  8
#define N_   1024
#define EPS_ 1e-6f
#define INV_TEMP 0.17677669529663687f   /* 1/sqrt(32) */
#define INV_PI   0.3183098861837907f
#define LOG2E    1.4426950408889634f
#define CLAMP_   0.999999f              /* 1 - 1e-6 */

typedef __attribute__((ext_vector_type(8))) short bf16x8;
typedef __attribute__((ext_vector_type(4))) float f32x4;

__device__ __forceinline__ f32x4 mfma16(bf16x8 a, bf16x8 b, f32x4 c) {
    return __builtin_amdgcn_mfma_f32_16x16x32_bf16(a, b, c, 0, 0, 0);
}

__device__ __forceinline__ float mishf(float x) {
    float sp = (x > 20.f) ? x : log1pf(expf(x));
    return x * tanhf(sp);
}

// Hastings acos approx, abs err ~6.8e-5 rad
__device__ __forceinline__ float fast_acosf(float c) {
    float a = fabsf(c);
    float p = -0.0187293f;
    p = fmaf(p, a, 0.0742610f);
    p = fmaf(p, a, -0.2121144f);
    p = fmaf(p, a, 1.5707288f);
    float r = p * sqrtf(1.0f - a);
    return (c < 0.0f) ? (3.14159265358979f - r) : r;
}

__device__ __forceinline__ unsigned bf16r(float x) {   // RNE f32->bf16 bits
    unsigned b = __float_as_uint(x);
    return (b + 0x7fffu + ((b >> 16) & 1u)) >> 16;
}

// ---------------- Kernel 1: q,k,v grouped conv + BN affine + mish ----------
// q,k written fp32 [bh][d][n]; v written bf16 [bh][d][n] directly.
__global__ __launch_bounds__(256) void qkv_kernel(
    const float* __restrict__ x,
    const float* __restrict__ qw, const float* __restrict__ qb2,
    const float* __restrict__ qs, const float* __restrict__ qbeta,
    const float* __restrict__ kw, const float* __restrict__ kb2,
    const float* __restrict__ ks, const float* __restrict__ kbeta,
    const float* __restrict__ vw, const float* __restrict__ vb2,
    const float* __restrict__ vs, const float* __restrict__ vbeta,
    float* __restrict__ q, float* __restrict__ k, unsigned short* __restrict__ vbf)
{
    int id = blockIdx.x * 256 + threadIdx.x;     // (b, co, n)
    int n  = id & (N_ - 1);
    int co = (id >> 10) & 255;
    int b  = id >> 18;
    int g  = co >> 5;
    const float* xp = x + ((size_t)b * C_ + g * 32) * N_ + n;
    float accq = 0.f, acck = 0.f, accv = 0.f;
#pragma unroll
    for (int i = 0; i < 32; ++i) {
        float xv = xp[(size_t)i * N_];
        accq = fmaf(xv, qw[co * 32 + i], accq);
        acck = fmaf(xv, kw[co * 32 + i], acck);
        accv = fmaf(xv, vw[co * 32 + i], accv);
    }
    float yq = mishf(qs[co] * (accq + qb2[co]) + qbeta[co]) * INV_TEMP;
    float yk = mishf(ks[co] * (acck + kb2[co]) + kbeta[co]);
    float yv = mishf(vs[co] * (accv + vb2[co]) + vbeta[co]);
    q[id] = yq; k[id] = yk; vbf[id] = (unsigned short)bf16r(yv);
}

// ---------------- Kernel 1b: hi/lo pack + reciprocal norms -----------------
// qpk/kpk rows of 128B per (bh,n): bytes [0..63]=hi bf16 d0..31, [64..127]=lo.
__global__ __launch_bounds__(256) void pack_kernel(
    const float* __restrict__ q, const float* __restrict__ k,
    uint4* __restrict__ qpk, uint4* __restrict__ kpk,
    float* __restrict__ invqn, float* __restrict__ invkn)
{
    int id = blockIdx.x * 256 + threadIdx.x;     // (bh, n)
    int n  = id & (N_ - 1);
    int bh = id >> 10;
    const float* qp = q + (size_t)bh * 32 * N_ + n;
    const float* kp = k + (size_t)bh * 32 * N_ + n;
    unsigned qrow[32], krow[32];
    float sq = 0.f, sk = 0.f;
#pragma unroll
    for (int d = 0; d < 32; d += 2) {
        float a0 = qp[(size_t)d * N_], a1 = qp[(size_t)(d + 1) * N_];
        sq = fmaf(a0, a0, sq); sq = fmaf(a1, a1, sq);
        unsigned h0 = bf16r(a0), h1 = bf16r(a1);
        float r0 = a0 - __uint_as_float(h0 << 16);
        float r1 = a1 - __uint_as_float(h1 << 16);
        qrow[d >> 1] = h0 | (h1 << 16);
        qrow[16 + (d >> 1)] = bf16r(r0) | (bf16r(r1) << 16);
        float c0 = kp[(size_t)d * N_], c1 = kp[(size_t)(d + 1) * N_];
        sk = fmaf(c0, c0, sk); sk = fmaf(c1, c1, sk);
        unsigned g0 = bf16r(c0), g1 = bf16r(c1);
        float s0 = c0 - __uint_as_float(g0 << 16);
        float s1 = c1 - __uint_as_float(g1 << 16);
        krow[d >> 1] = g0 | (g1 << 16);
        krow[16 + (d >> 1)] = bf16r(s0) | (bf16r(s1) << 16);
    }
    invqn[id] = 1.0f / fmaxf(sqrtf(sq), 1e-12f);
    invkn[id] = 1.0f / fmaxf(sqrtf(sk), 1e-12f);
    uint4* qd = qpk + (size_t)id * 8;
    uint4* kd = kpk + (size_t)id * 8;
#pragma unroll
    for (int j = 0; j < 8; ++j) {
        qd[j] = make_uint4(qrow[4 * j], qrow[4 * j + 1], qrow[4 * j + 2], qrow[4 * j + 3]);
        kd[j] = make_uint4(krow[4 * j], krow[4 * j + 1], krow[4 * j + 2], krow[4 * j + 3]);
    }
}

// ---------------- Kernel 2: attention (MFMA, two-sweep) --------------------
// Block: 4 waves, one (b,h), 64 q-rows. Wave w owns rows w*16..+16.
// m swept in 8 chunks of 128. Staging via global_load_lds with
// pre-swizzled global sources (linear LDS dest, XOR key on 16B granule).
__global__ __launch_bounds__(256) void attn_kernel(
    const uint4* __restrict__ qpk, const uint4* __restrict__ kpk,
    const unsigned short* __restrict__ vbf,
    const float* __restrict__ invqn, const float* __restrict__ invkn,
    float* __restrict__ aout, float* __restrict__ ampart)
{
    __shared__ __align__(16) unsigned short Qs[64 * 64];    // 8 KB
    __shared__ __align__(16) unsigned short Ks[128 * 64];   // 16 KB
    __shared__ __align__(16) unsigned short Vs[32 * 128];   // 8 KB
    __shared__ __align__(16) unsigned short Ps[4 * 16 * 128]; // 16 KB
    __shared__ __align__(16) float amW[N_];                 // 4 KB
    __shared__ __align__(16) float invknS[128];

    const int tid  = threadIdx.x;
    const int wave = tid >> 6, lane = tid & 63;
    const int blk = blockIdx.x;
    const int itile = blk & 15;
    const int bh    = blk >> 4;
    const int i0    = itile * 64;
    const int l15 = lane & 15, lg = lane >> 4;

    // ---- stage Qs (512 granules, pre-swizzled src) + zero amW ----
    {
        const char* qsrc = (const char*)qpk + ((size_t)(bh * N_ + i0) << 7);
#pragma unroll
        for (int p = 0; p < 2; ++p) {
            int g = p * 256 + wave * 64 + lane;
            int i = g >> 3, s = g & 7;
            __builtin_amdgcn_global_load_lds(
                (const __attribute__((address_space(1))) void*)(qsrc + i * 128 + ((s ^ (i & 7)) << 4)),
                (__attribute__((address_space(3))) void*)((char*)Qs + ((p * 256 + wave * 64) << 4)),
                16, 0, 0);
        }
        for (int j = tid; j < N_; j += 256) amW[j] = 0.f;
    }
    float invq[4];
#pragma unroll
    for (int r = 0; r < 4; ++r)
        invq[r] = invqn[bh * N_ + i0 + wave * 16 + lg * 4 + r];

    float rs[4] = {0.f, 0.f, 0.f, 0.f};
    const char* ksrc = (const char*)kpk + ((size_t)bh * N_ << 7);
    const char* vsrc = (const char*)vbf + ((size_t)bh * 32 * N_ << 1);

    // ================= sweep 1: row sums =================
    for (int ch = 0; ch < 8; ++ch) {
        int m0 = ch * 128;
        __syncthreads();
        {
#pragma unroll
            for (int p = 0; p < 4; ++p) {
                int g = p * 256 + wave * 64 + lane;
                int m = g >> 3, s = g & 7;
                __builtin_amdgcn_global_load_lds(
                    (const __attribute__((address_space(1))) void*)(ksrc + (size_t)(m0 + m) * 128 + ((s ^ (m & 7)) << 4)),
                    (__attribute__((address_space(3))) void*)((char*)Ks + ((p * 256 + wave * 64) << 4)),
                    16, 0, 0);
            }
            if (tid < 128) invknS[tid] = invkn[bh * N_ + m0 + tid];
        }
        __syncthreads();

        int il = wave * 16 + l15;
        const char* qrow = (const char*)Qs + il * 128;
        bf16x8 ahi = *(const bf16x8*)(qrow + ((lg ^ (il & 7)) << 4));
        bf16x8 alo = *(const bf16x8*)(qrow + (((4 + lg) ^ (il & 7)) << 4));
#pragma unroll
        for (int t = 0; t < 8; ++t) {
            int mr = t * 16 + l15;
            const char* krow = (const char*)Ks + mr * 128;
            bf16x8 bhi = *(const bf16x8*)(krow + ((lg ^ (mr & 7)) << 4));
            bf16x8 blo = *(const bf16x8*)(krow + (((4 + lg) ^ (mr & 7)) << 4));
            f32x4 cf = {0.f, 0.f, 0.f, 0.f};
            cf = mfma16(ahi, bhi, cf);
            cf = mfma16(alo, bhi, cf);
            cf = mfma16(ahi, blo, cf);
            float ikc = invknS[mr];
#pragma unroll
            for (int r = 0; r < 4; ++r) {
                float cc = cf[r] * invq[r] * ikc;
                cc = __builtin_amdgcn_fmed3f(cc, -CLAMP_, CLAMP_);
                float ee = exp2f(fmaf(fast_acosf(cc), -(LOG2E * INV_PI), LOG2E));
                rs[r] += ee;
            }
        }
    }
    // reduce across the 16-lane group sharing rows
    float rinv[4];
#pragma unroll
    for (int r = 0; r < 4; ++r) {
        float s = rs[r];
        s += __shfl_xor(s, 1); s += __shfl_xor(s, 2);
        s += __shfl_xor(s, 4); s += __shfl_xor(s, 8);
        rinv[r] = __builtin_amdgcn_rcpf(s);
    }

    // ================= sweep 2: P, am, PV =================
    f32x4 o0 = {0.f, 0.f, 0.f, 0.f}, o1 = {0.f, 0.f, 0.f, 0.f};
    for (int ch = 0; ch < 8; ++ch) {
        int m0 = ch * 128;
        __syncthreads();
        {
#pragma unroll
            for (int p = 0; p < 4; ++p) {
                int g = p * 256 + wave * 64 + lane;
                int m = g >> 3, s = g & 7;
                __builtin_amdgcn_global_load_lds(
                    (const __attribute__((address_space(1))) void*)(ksrc + (size_t)(m0 + m) * 128 + ((s ^ (m & 7)) << 4)),
                    (__attribute__((address_space(3))) void*)((char*)Ks + ((p * 256 + wave * 64) << 4)),
                    16, 0, 0);
            }
#pragma unroll
            for (int p = 0; p < 2; ++p) {
                int g = p * 256 + wave * 64 + lane;
                int d = g >> 4, gr = g & 15;
                __builtin_amdgcn_global_load_lds(
                    (const __attribute__((address_space(1))) void*)(vsrc + (size_t)d * 2048 + (size_t)m0 * 2 + ((gr ^ (d & 7)) << 4)),
                    (__attribute__((address_space(3))) void*)((char*)Vs + ((p * 256 + wave * 64) << 4)),
                    16, 0, 0);
            }
            if (tid < 128) invknS[tid] = invkn[bh * N_ + m0 + tid];
        }
        __syncthreads();

        int il = wave * 16 + l15;
        const char* qrow = (const char*)Qs + il * 128;
        bf16x8 ahi = *(const bf16x8*)(qrow + ((lg ^ (il & 7)) << 4));
        bf16x8 alo = *(const bf16x8*)(qrow + (((4 + lg) ^ (il & 7)) << 4));
#pragma unroll
        for (int t = 0; t < 8; ++t) {
            int mr = t * 16 + l15;
            const char* krow = (const char*)Ks + mr * 128;
            bf16x8 bhi = *(const bf16x8*)(krow + ((lg ^ (mr & 7)) << 4));
            bf16x8 blo = *(const bf16x8*)(krow + (((4 + lg) ^ (mr & 7)) << 4));
            f32x4 cf = {0.f, 0.f, 0.f, 0.f};
            cf = mfma16(ahi, bhi, cf);
            cf = mfma16(alo, bhi, cf);
            cf = mfma16(ahi, blo, cf);
            float ikc = invknS[mr];
            float csum = 0.f;
#pragma unroll
            for (int r = 0; r < 4; ++r) {
                float cc = cf[r] * invq[r] * ikc;
                cc = __builtin_amdgcn_fmed3f(cc, -CLAMP_, CLAMP_);
                float pp = exp2f(fmaf(fast_acosf(cc), -(LOG2E * INV_PI), LOG2E)) * rinv[r];
                csum += pp;
                int il2 = lg * 4 + r;
                *(unsigned short*)((char*)Ps + wave * 4096 + il2 * 256 +
                                   (((mr >> 3) ^ (il2 & 7)) << 4) + ((mr & 7) << 1)) =
                    (unsigned short)bf16r(pp);
            }
            // column sum across the 4 row-groups, then one LDS atomic
            csum += __shfl_xor(csum, 16);
            csum += __shfl_xor(csum, 32);
            if (lane < 16) atomicAdd(&amW[m0 + t * 16 + lane], csum);
        }
        asm volatile("s_waitcnt lgkmcnt(0)" ::: "memory");
        __builtin_amdgcn_sched_barrier(0);
        // PV: o[i][d] += P[i][m] * V[m][d]
#pragma unroll
        for (int kss = 0; kss < 4; ++kss) {
            int gp = kss * 4 + lg;
            bf16x8 pa = *(const bf16x8*)((const char*)Ps + wave * 4096 + l15 * 256 +
                                         ((gp ^ (l15 & 7)) << 4));
            {
                int dr = l15;
                bf16x8 vb = *(const bf16x8*)((const char*)Vs + dr * 256 + ((gp ^ (dr & 7)) << 4));
                o0 = mfma16(pa, vb, o0);
            }
            {
                int dr = 16 + l15;
                bf16x8 vb = *(const bf16x8*)((const char*)Vs + dr * 256 + ((gp ^ (dr & 7)) << 4));
                o1 = mfma16(pa, vb, o1);
            }
        }
    }

    // ---- epilogue: write O (f32) and am partials ----
    {
        int ibase = i0 + wave * 16 + lg * 4;
        *(f32x4*)&aout[((size_t)bh * 32 + l15) * N_ + ibase] = o0;
        *(f32x4*)&aout[((size_t)bh * 32 + 16 + l15) * N_ + ibase] = o1;
    }
    __syncthreads();
    for (int j = tid; j < N_; j += 256)
        ampart[(size_t)blk * N_ + j] = amW[j];
}

// ---------------- Kernel 3: attention-map reduce + min/max normalize -------
__global__ __launch_bounds__(256) void am_kernel(
    const float* __restrict__ amp, float* __restrict__ outAm)
{
    int b = blockIdx.x, tid = threadIdx.x;
    float s[4] = {0.f, 0.f, 0.f, 0.f};
    const float* base = amp + (size_t)b * 128 * N_;
    for (int p = 0; p < 128; ++p) {
#pragma unroll
        for (int c2 = 0; c2 < 4; ++c2)
            s[c2] += base[(size_t)p * N_ + tid + 256 * c2];
    }
    float mn = fminf(fminf(s[0], s[1]), fminf(s[2], s[3]));
    float mx = fmaxf(fmaxf(s[0], s[1]), fmaxf(s[2], s[3]));
    __shared__ float rmn[256], rmx[256];
    rmn[tid] = mn; rmx[tid] = mx;
    __syncthreads();
    for (int off = 128; off >= 1; off >>= 1) {
        if (tid < off) {
            rmn[tid] = fminf(rmn[tid], rmn[tid + off]);
            rmx[tid] = fmaxf(rmx[tid], rmx[tid + off]);
        }
        __syncthreads();
    }
    mn = rmn[0]; mx = rmx[0];
    float inv = 1.f / (mx - mn);
#pragma unroll
    for (int c2 = 0; c2 < 4; ++c2)
        outAm[(size_t)b * N_ + tid + 256 * c2] = (s[c2] - mn) * inv;
}

// ---------------- Kernel 4: final 1x1 conv + mish + residual ---------------
// 4 output channels per thread (co, co+64, co+128, co+192) -> 4x less L2 read.
__global__ __launch_bounds__(256) void fconv_kernel(
    const float* __restrict__ aout, const float* __restrict__ x,
    const float* __restrict__ fw, const float* __restrict__ fb,
    const float* __restrict__ fs, const float* __restrict__ fbeta,
    float* __restrict__ y)
{
    int id = blockIdx.x * 256 + threadIdx.x;     // (b, cq, n)
    int n  = id & (N_ - 1);
    int cq = (id >> 10) & 63;
    int b  = id >> 16;
    const float* ap = aout + (size_t)b * C_ * N_ + n;
    float acc[4] = {0.f, 0.f, 0.f, 0.f};
#pragma unroll 8
    for (int ci = 0; ci < 256; ++ci) {
        float av = ap[(size_t)ci * N_];
#pragma unroll
        for (int j = 0; j < 4; ++j)
            acc[j] = fmaf(av, fw[(cq + 64 * j) * C_ + ci], acc[j]);
    }
#pragma unroll
    for (int j = 0; j < 4; ++j) {
        int co = cq + 64 * j;
        size_t oid = ((size_t)b * C_ + co) * N_ + n;
        y[oid] = mishf(fs[co] * (acc[j] + fb[co]) + fbeta[co]) + x[oid];
    }
}

extern "C" void kernel_launch(void* const* d_in, const int* in_sizes, int n_in,
                              void* d_out, int out_size, void* d_ws, size_t ws_size,
                              hipStream_t stream)
{
    const float* x     = (const float*)d_in[0];
    const float* q_w   = (const float*)d_in[1];
    const float* q_b   = (const float*)d_in[2];
    const float* q_s   = (const float*)d_in[3];
    const float* q_be  = (const float*)d_in[4];
    const float* k_w   = (const float*)d_in[5];
    const float* k_b   = (const float*)d_in[6];
    const float* k_s   = (const float*)d_in[7];
    const float* k_be  = (const float*)d_in[8];
    const float* v_w   = (const float*)d_in[9];
    const float* v_b   = (const float*)d_in[10];
    const float* v_s   = (const float*)d_in[11];
    const float* v_be  = (const float*)d_in[12];
    const float* f_w   = (const float*)d_in[13];
    const float* f_b   = (const float*)d_in[14];
    const float* f_s   = (const float*)d_in[15];
    const float* f_be  = (const float*)d_in[16];

    float* y_out  = (float*)d_out;                        // (8,256,32,32)
    float* am_out = (float*)d_out + (size_t)B_ * C_ * N_; // (8,32,32)

    char* ws = (char*)d_ws;
    float* q      = (float*)ws;                 ws += (size_t)B_ * C_ * N_ * 4;   // 8MB
    float* k      = (float*)ws;                 ws += (size_t)B_ * C_ * N_ * 4;   // 8MB
    uint4* qpk    = (uint4*)ws;                 ws += (size_t)B_ * NH_ * N_ * 128; // 8MB
    uint4* kpk    = (uint4*)ws;                 ws += (size_t)B_ * NH_ * N_ * 128; // 8MB
    unsigned short* vbf = (unsigned short*)ws;  ws += (size_t)B_ * C_ * N_ * 2;   // 4MB
    float* invqn  = (float*)ws;                 ws += (size_t)B_ * NH_ * N_ * 4;  // 256KB
    float* invkn  = (float*)ws;                 ws += (size_t)B_ * NH_ * N_ * 4;  // 256KB
    float* aout   = (float*)ws;                 ws += (size_t)B_ * C_ * N_ * 4;   // 8MB
    float* amp    = (float*)ws;                                                    // 4MB

    qkv_kernel<<<(B_ * C_ * N_) / 256, 256, 0, stream>>>(
        x, q_w, q_b, q_s, q_be, k_w, k_b, k_s, k_be,
        v_w, v_b, v_s, v_be, q, k, vbf);

    pack_kernel<<<(B_ * NH_ * N_) / 256, 256, 0, stream>>>(
        q, k, qpk, kpk, invqn, invkn);

    attn_kernel<<<B_ * NH_ * 16, 256, 0, stream>>>(
        qpk, kpk, vbf, invqn, invkn, aout, amp);

    am_kernel<<<B_, 256, 0, stream>>>(amp, am_out);

    fconv_kernel<<<(B_ * C_ * N_) / 1024, 256, 0, stream>>>(
        aout, x, f_w, f_b, f_s, f_be, y_out);
}

// Round 4
// 177.197 us; speedup vs baseline: 73.7735x; 1.6822x over previous
//
#include <hip/hip_runtime.h>
#include <math.h>

#define B_   8
#define C_   256
#define NH_  8
#define N_   1024
#define LOG2E    1.4426950408889634f
#define L2E_PI   0.45922409311f          /* log2(e)/pi */
#define CLAMP_   0.999999f               /* 1 - 1e-6 */

typedef __attribute__((ext_vector_type(8))) short bf16x8;
typedef __attribute__((ext_vector_type(4))) float f32x4;
typedef unsigned short u16;
typedef unsigned int u32;

__device__ __forceinline__ f32x4 mfma16(bf16x8 a, bf16x8 b, f32x4 c) {
    return __builtin_amdgcn_mfma_f32_16x16x32_bf16(a, b, c, 0, 0, 0);
}
__device__ __forceinline__ u32 bf16r(float x) {     // RNE f32->bf16 bits
    u32 b = __float_as_uint(x);
    return (b + 0x7fffu + ((b >> 16) & 1u)) >> 16;
}
// exact algebra: tanh(softplus(x)) = (e^2+2e)/(e^2+2e+2), e = exp(x)
__device__ __forceinline__ float mish_fast(float x) {
    float e  = __builtin_amdgcn_exp2f(fminf(x, 30.f) * LOG2E);
    float nm = e * (e + 2.f);
    return x * nm * __builtin_amdgcn_rcpf(nm + 2.f);
}
// Hastings acos approx, abs err ~6.8e-5 rad
__device__ __forceinline__ float fast_acosf(float c) {
    float a = fabsf(c);
    float p = fmaf(fmaf(fmaf(-0.0187293f, a, 0.0742610f), a, -0.2121144f), a, 1.5707288f);
    float r = p * __builtin_amdgcn_sqrtf(1.0f - a);
    return (c < 0.0f) ? (3.14159265358979f - r) : r;
}

// ---------------- Kernel 1: q,k,v grouped conv + BN affine + mish ----------
__global__ __launch_bounds__(256) void qkv_kernel(
    const float* __restrict__ x,
    const float* __restrict__ qw, const float* __restrict__ qb2,
    const float* __restrict__ qs, const float* __restrict__ qbeta,
    const float* __restrict__ kw, const float* __restrict__ kb2,
    const float* __restrict__ ks, const float* __restrict__ kbeta,
    const float* __restrict__ vw, const float* __restrict__ vb2,
    const float* __restrict__ vs, const float* __restrict__ vbeta,
    float* __restrict__ q, float* __restrict__ k, u16* __restrict__ vbf)
{
    int id = blockIdx.x * 256 + threadIdx.x;     // (b, co, n)
    int n  = id & (N_ - 1);
    int co = (id >> 10) & 255;
    int b  = id >> 18;
    int g  = co >> 5;
    const float* xp = x + ((size_t)b * C_ + g * 32) * N_ + n;
    float accq = 0.f, acck = 0.f, accv = 0.f;
#pragma unroll
    for (int i = 0; i < 32; ++i) {
        float xv = xp[(size_t)i * N_];
        accq = fmaf(xv, qw[co * 32 + i], accq);
        acck = fmaf(xv, kw[co * 32 + i], acck);
        accv = fmaf(xv, vw[co * 32 + i], accv);
    }
    // INV_TEMP omitted: q is normalized downstream, scale cancels in cos
    float yq = mish_fast(qs[co] * (accq + qb2[co]) + qbeta[co]);
    float yk = mish_fast(ks[co] * (acck + kb2[co]) + kbeta[co]);
    float yv = mish_fast(vs[co] * (accv + vb2[co]) + vbeta[co]);
    q[id] = yq; k[id] = yk; vbf[id] = (u16)bf16r(yv);
}

// ---------------- Kernel 1b: normalize rows + hi/lo bf16 pack --------------
// qpk/kpk rows of 128B per (bh,n): bytes [0..63]=hi bf16 d0..31, [64..127]=lo.
__global__ __launch_bounds__(256) void pack_kernel(
    const float* __restrict__ q, const float* __restrict__ k,
    uint4* __restrict__ qpk, uint4* __restrict__ kpk)
{
    int id = blockIdx.x * 256 + threadIdx.x;     // (bh, n)
    int n  = id & (N_ - 1);
    int bh = id >> 10;
    const float* qp = q + (size_t)bh * 32 * N_ + n;
    const float* kp = k + (size_t)bh * 32 * N_ + n;
    float va[32];
    u32 hi[16], lo[16];

    // ---- q ----
    float sq = 0.f;
#pragma unroll
    for (int d = 0; d < 32; ++d) { va[d] = qp[(size_t)d * N_]; sq = fmaf(va[d], va[d], sq); }
    float inv = __builtin_amdgcn_rsqf(fmaxf(sq, 1e-24f));
#pragma unroll
    for (int d = 0; d < 32; d += 2) {
        float a0 = va[d] * inv, a1 = va[d + 1] * inv;
        u32 h0 = bf16r(a0), h1 = bf16r(a1);
        float r0 = a0 - __uint_as_float(h0 << 16);
        float r1 = a1 - __uint_as_float(h1 << 16);
        hi[d >> 1] = h0 | (h1 << 16);
        lo[d >> 1] = bf16r(r0) | (bf16r(r1) << 16);
    }
    uint4* qd = qpk + (size_t)id * 8;
#pragma unroll
    for (int j = 0; j < 4; ++j) {
        qd[j]     = make_uint4(hi[4 * j], hi[4 * j + 1], hi[4 * j + 2], hi[4 * j + 3]);
        qd[4 + j] = make_uint4(lo[4 * j], lo[4 * j + 1], lo[4 * j + 2], lo[4 * j + 3]);
    }
    // ---- k ----
    float sk = 0.f;
#pragma unroll
    for (int d = 0; d < 32; ++d) { va[d] = kp[(size_t)d * N_]; sk = fmaf(va[d], va[d], sk); }
    inv = __builtin_amdgcn_rsqf(fmaxf(sk, 1e-24f));
#pragma unroll
    for (int d = 0; d < 32; d += 2) {
        float a0 = va[d] * inv, a1 = va[d + 1] * inv;
        u32 h0 = bf16r(a0), h1 = bf16r(a1);
        float r0 = a0 - __uint_as_float(h0 << 16);
        float r1 = a1 - __uint_as_float(h1 << 16);
        hi[d >> 1] = h0 | (h1 << 16);
        lo[d >> 1] = bf16r(r0) | (bf16r(r1) << 16);
    }
    uint4* kd = kpk + (size_t)id * 8;
#pragma unroll
    for (int j = 0; j < 4; ++j) {
        kd[j]     = make_uint4(hi[4 * j], hi[4 * j + 1], hi[4 * j + 2], hi[4 * j + 3]);
        kd[4 + j] = make_uint4(lo[4 * j], lo[4 * j + 1], lo[4 * j + 2], lo[4 * j + 3]);
    }
}

// ---------------- Kernel 1c: f_w -> bf16 -----------------------------------
__global__ __launch_bounds__(256) void wcvt_kernel(
    const float* __restrict__ fw, u16* __restrict__ wbf)
{
    int id = blockIdx.x * 1024 + threadIdx.x;
#pragma unroll
    for (int j = 0; j < 4; ++j) { int p = id + j * 256; wbf[p] = (u16)bf16r(fw[p]); }
}

// ---------------- Kernel 2: attention (MFMA two-sweep, normalized ops) -----
// Block: 4 waves, one (b,h), 64 q-rows; m swept in 8 chunks of 128.
// cos comes directly from hi/lo MFMA of normalized rows. P stored raw (e),
// rinv deferred to am-weighting and O epilogue scale.
__global__ __launch_bounds__(256) void attn_kernel(
    const uint4* __restrict__ qpk, const uint4* __restrict__ kpk,
    const u16* __restrict__ vbf,
    u16* __restrict__ aout_bt, float* __restrict__ ampart)
{
    __shared__ __align__(16) u16 Qs[64 * 64];      // 8 KB
    __shared__ __align__(16) u16 Ks[128 * 64];     // 16 KB
    __shared__ __align__(16) u16 Vs[32 * 128];     // 8 KB
    __shared__ __align__(16) u16 Ps[4][16 * 136];  // 17 KB, rows padded 272B
    __shared__ __align__(16) float amW[N_];        // 4 KB

    const int tid  = threadIdx.x;
    const int wave = tid >> 6, lane = tid & 63;
    const int blk   = blockIdx.x;
    const int itile = blk & 15;
    const int bh    = blk >> 4;
    const int h     = bh & 7, bidx = bh >> 3;
    const int i0    = itile * 64;
    const int l15 = lane & 15, lg = lane >> 4;

    // ---- stage Qs (512 granules, pre-swizzled src) + zero amW ----
    {
        const char* qsrc = (const char*)qpk + ((size_t)(bh * N_ + i0) << 7);
#pragma unroll
        for (int p = 0; p < 2; ++p) {
            int g = p * 256 + wave * 64 + lane;
            int i = g >> 3, s = g & 7;
            __builtin_amdgcn_global_load_lds(
                (const __attribute__((address_space(1))) void*)(qsrc + i * 128 + ((s ^ (i & 7)) << 4)),
                (__attribute__((address_space(3))) void*)((char*)Qs + ((p * 256 + wave * 64) << 4)),
                16, 0, 0);
        }
        for (int j = tid; j < N_; j += 256) amW[j] = 0.f;
    }
    const char* ksrc = (const char*)kpk + ((size_t)bh * N_ << 7);
    const char* vsrc = (const char*)(vbf + (size_t)bh * 32 * N_);

    __syncthreads();
    // hoisted Q frags (constant across chunks and sweeps)
    const char* qrow = (const char*)Qs + (wave * 16 + l15) * 128;
    bf16x8 ahi = *(const bf16x8*)(qrow + ((lg ^ (l15 & 7)) << 4));
    bf16x8 alo = *(const bf16x8*)(qrow + (((4 + lg) ^ (l15 & 7)) << 4));
    // K frag bases: swizzle key for row mr=(t*16+l15) is l15&7, t-invariant
    const char* kb0 = (const char*)Ks + l15 * 128 + ((lg ^ (l15 & 7)) << 4);
    const char* kb1 = (const char*)Ks + l15 * 128 + (((4 + lg) ^ (l15 & 7)) << 4);

    float rs[4] = {0.f, 0.f, 0.f, 0.f};

    // ================= sweep 1: row sums =================
    for (int ch = 0; ch < 8; ++ch) {
        int m0 = ch * 128;
        __syncthreads();
#pragma unroll
        for (int p = 0; p < 4; ++p) {
            int g = p * 256 + wave * 64 + lane;
            int m = g >> 3, s = g & 7;
            __builtin_amdgcn_global_load_lds(
                (const __attribute__((address_space(1))) void*)(ksrc + (size_t)(m0 + m) * 128 + ((s ^ (m & 7)) << 4)),
                (__attribute__((address_space(3))) void*)((char*)Ks + ((p * 256 + wave * 64) << 4)),
                16, 0, 0);
        }
        __syncthreads();
#pragma unroll
        for (int t = 0; t < 8; ++t) {
            bf16x8 bhi = *(const bf16x8*)(kb0 + t * 2048);
            bf16x8 blo = *(const bf16x8*)(kb1 + t * 2048);
            f32x4 cf = {0.f, 0.f, 0.f, 0.f};
            cf = mfma16(ahi, bhi, cf);
            cf = mfma16(alo, bhi, cf);
            cf = mfma16(ahi, blo, cf);
#pragma unroll
            for (int r = 0; r < 4; ++r) {
                float cc = __builtin_amdgcn_fmed3f(cf[r], -CLAMP_, CLAMP_);
                rs[r] += __builtin_amdgcn_exp2f(fmaf(fast_acosf(cc), -L2E_PI, LOG2E));
            }
        }
    }
    float rinv[4];
#pragma unroll
    for (int r = 0; r < 4; ++r) {
        float s = rs[r];
        s += __shfl_xor(s, 1); s += __shfl_xor(s, 2);
        s += __shfl_xor(s, 4); s += __shfl_xor(s, 8);
        rinv[r] = __builtin_amdgcn_rcpf(s);
    }

    // ================= sweep 2: P(raw), am, PV =================
    f32x4 o0 = {0.f, 0.f, 0.f, 0.f}, o1 = {0.f, 0.f, 0.f, 0.f};
    char* psw = (char*)&Ps[wave][0] + lg * 1088 + l15 * 2;       // write base
    const char* pab = (const char*)&Ps[wave][0] + l15 * 272 + lg * 16; // read base
    const int s0 = lg ^ (l15 & 7);
    const int vbase = l15 * 256 + (s0 << 4);

    for (int ch = 0; ch < 8; ++ch) {
        int m0 = ch * 128;
        __syncthreads();
#pragma unroll
        for (int p = 0; p < 4; ++p) {
            int g = p * 256 + wave * 64 + lane;
            int m = g >> 3, s = g & 7;
            __builtin_amdgcn_global_load_lds(
                (const __attribute__((address_space(1))) void*)(ksrc + (size_t)(m0 + m) * 128 + ((s ^ (m & 7)) << 4)),
                (__attribute__((address_space(3))) void*)((char*)Ks + ((p * 256 + wave * 64) << 4)),
                16, 0, 0);
        }
#pragma unroll
        for (int p = 0; p < 2; ++p) {
            int g = p * 256 + wave * 64 + lane;
            int d = g >> 4, gr = g & 15;
            __builtin_amdgcn_global_load_lds(
                (const __attribute__((address_space(1))) void*)(vsrc + (size_t)d * 2048 + (size_t)m0 * 2 + ((gr ^ (d & 7)) << 4)),
                (__attribute__((address_space(3))) void*)((char*)Vs + ((p * 256 + wave * 64) << 4)),
                16, 0, 0);
        }
        __syncthreads();

#pragma unroll
        for (int t = 0; t < 8; ++t) {
            bf16x8 bhi = *(const bf16x8*)(kb0 + t * 2048);
            bf16x8 blo = *(const bf16x8*)(kb1 + t * 2048);
            f32x4 cf = {0.f, 0.f, 0.f, 0.f};
            cf = mfma16(ahi, bhi, cf);
            cf = mfma16(alo, bhi, cf);
            cf = mfma16(ahi, blo, cf);
            float csum = 0.f;
#pragma unroll
            for (int r = 0; r < 4; ++r) {
                float cc = __builtin_amdgcn_fmed3f(cf[r], -CLAMP_, CLAMP_);
                float ee = __builtin_amdgcn_exp2f(fmaf(fast_acosf(cc), -L2E_PI, LOG2E));
                csum = fmaf(ee, rinv[r], csum);
                *(u16*)(psw + r * 272 + t * 32) = (u16)bf16r(ee);
            }
            csum += __shfl_xor(csum, 16);
            csum += __shfl_xor(csum, 32);
            if (lane < 16) atomicAdd(&amW[m0 + t * 16 + lane], csum);
        }
        asm volatile("s_waitcnt lgkmcnt(0)" ::: "memory");
        __builtin_amdgcn_sched_barrier(0);
#pragma unroll
        for (int kss = 0; kss < 4; ++kss) {
            bf16x8 pa = *(const bf16x8*)(pab + kss * 64);
            int va = vbase ^ (kss << 6);
            bf16x8 v0 = *(const bf16x8*)((const char*)Vs + va);
            bf16x8 v1 = *(const bf16x8*)((const char*)Vs + va + 4096);
            o0 = mfma16(pa, v0, o0);
            o1 = mfma16(pa, v1, o1);
        }
    }
    __syncthreads();   // amW atomics complete; Ps free for reuse

    // ---- epilogue: scale by rinv, transpose via LDS, store bf16 [b][n][c] ----
    {
        u16* oT = (u16*)Ps;                       // [64 rows][40 u16] (80B rows)
#pragma unroll
        for (int r = 0; r < 4; ++r) {
            int i = wave * 16 + lg * 4 + r;
            oT[i * 40 + l15]      = (u16)bf16r(o0[r] * rinv[r]);
            oT[i * 40 + 16 + l15] = (u16)bf16r(o1[r] * rinv[r]);
        }
    }
    __syncthreads();
    {
        const u16* oT = (const u16*)Ps;
        int row = tid >> 2, c4 = tid & 3;
        uint4 val = *(const uint4*)((const char*)oT + row * 80 + c4 * 16);
        int g = h * 4 + c4;                       // logical 16B granule in row
        size_t dst = ((size_t)(bidx * N_ + i0 + row) << 9) + ((size_t)((g ^ (row & 7)) << 4));
        *(uint4*)((char*)aout_bt + dst) = val;
    }
    for (int j = tid; j < N_; j += 256)
        ampart[(size_t)blk * N_ + j] = amW[j];
}

// ---------------- Kernel 3a/3b: attention-map two-level reduce -------------
__global__ __launch_bounds__(256) void am1_kernel(
    const float* __restrict__ amp, float* __restrict__ tmp)
{
    int blk = blockIdx.x, tid = threadIdx.x;     // b*16 + g
    const float* base = amp + (size_t)blk * 8 * N_;
    float s[4] = {0.f, 0.f, 0.f, 0.f};
    for (int p = 0; p < 8; ++p) {
#pragma unroll
        for (int c2 = 0; c2 < 4; ++c2)
            s[c2] += base[(size_t)p * N_ + tid + 256 * c2];
    }
#pragma unroll
    for (int c2 = 0; c2 < 4; ++c2)
        tmp[(size_t)blk * N_ + tid + 256 * c2] = s[c2];
}

__global__ __launch_bounds__(256) void am2_kernel(
    const float* __restrict__ tmp, float* __restrict__ outAm)
{
    int b = blockIdx.x, tid = threadIdx.x;
    const float* base = tmp + (size_t)b * 16 * N_;
    float s[4] = {0.f, 0.f, 0.f, 0.f};
    for (int p = 0; p < 16; ++p) {
#pragma unroll
        for (int c2 = 0; c2 < 4; ++c2)
            s[c2] += base[(size_t)p * N_ + tid + 256 * c2];
    }
    float mn = fminf(fminf(s[0], s[1]), fminf(s[2], s[3]));
    float mx = fmaxf(fmaxf(s[0], s[1]), fmaxf(s[2], s[3]));
    __shared__ float rmn[256], rmx[256];
    rmn[tid] = mn; rmx[tid] = mx;
    __syncthreads();
    for (int off = 128; off >= 1; off >>= 1) {
        if (tid < off) {
            rmn[tid] = fminf(rmn[tid], rmn[tid + off]);
            rmx[tid] = fmaxf(rmx[tid], rmx[tid + off]);
        }
        __syncthreads();
    }
    mn = rmn[0]; mx = rmx[0];
    float inv = 1.f / (mx - mn);
#pragma unroll
    for (int c2 = 0; c2 < 4; ++c2)
        outAm[(size_t)b * N_ + tid + 256 * c2] = (s[c2] - mn) * inv;
}

// ---------------- Kernel 4: final 1x1 conv (MFMA) + mish + residual --------
// Block: (b, 32-n tile); Y[co,n] = W[co,:]·A[:,n]. A staged bf16 in LDS
// (granules pre-swizzled at attn-write time), W bf16 frags from L2.
__global__ __launch_bounds__(256) void fconv_kernel(
    const u16* __restrict__ aout_bt, const u16* __restrict__ wbf,
    const float* __restrict__ x,
    const float* __restrict__ fs, const float* __restrict__ fb,
    const float* __restrict__ fbeta, float* __restrict__ y)
{
    __shared__ __align__(16) u16 As[32 * 256];   // 16 KB [n][c] swizzled
    const int tid  = threadIdx.x;
    const int wave = tid >> 6, lane = tid & 63;
    const int l15 = lane & 15, lg = lane >> 4;
    const int b  = blockIdx.x >> 5;
    const int n0 = (blockIdx.x & 31) * 32;

    const char* asrc = (const char*)aout_bt + ((size_t)(b * N_ + n0) << 9);
#pragma unroll
    for (int p = 0; p < 4; ++p) {
        int g = p * 256 + wave * 64 + lane;
        __builtin_amdgcn_global_load_lds(
            (const __attribute__((address_space(1))) void*)(asrc + g * 16),
            (__attribute__((address_space(3))) void*)((char*)As + ((p * 256 + wave * 64) << 4)),
            16, 0, 0);
    }
    __syncthreads();

    f32x4 acc[4][2];
#pragma unroll
    for (int f = 0; f < 4; ++f)
#pragma unroll
        for (int fn = 0; fn < 2; ++fn) acc[f][fn] = (f32x4){0.f, 0.f, 0.f, 0.f};

    const int cobase = wave * 64;
#pragma unroll
    for (int kk = 0; kk < 8; ++kk) {
        bf16x8 af[2];
#pragma unroll
        for (int fn = 0; fn < 2; ++fn) {
            int nf = fn * 16 + l15;
            af[fn] = *(const bf16x8*)((const char*)As + nf * 512 +
                                      (((kk * 4 + lg) ^ (nf & 7)) << 4));
        }
#pragma unroll
        for (int f = 0; f < 4; ++f) {
            bf16x8 wf = *(const bf16x8*)(wbf + (size_t)(cobase + f * 16 + l15) * 256 + kk * 32 + lg * 8);
            acc[f][0] = mfma16(wf, af[0], acc[f][0]);
            acc[f][1] = mfma16(wf, af[1], acc[f][1]);
        }
    }

#pragma unroll
    for (int f = 0; f < 4; ++f) {
#pragma unroll
        for (int r = 0; r < 4; ++r) {
            int co = cobase + f * 16 + lg * 4 + r;
            float sc = fs[co], bb = fb[co], bt = fbeta[co];
#pragma unroll
            for (int fn = 0; fn < 2; ++fn) {
                int n = n0 + fn * 16 + l15;
                size_t oid = ((size_t)(b * C_ + co) << 10) + n;
                y[oid] = mish_fast(sc * (acc[f][fn][r] + bb) + bt) + x[oid];
            }
        }
    }
}

extern "C" void kernel_launch(void* const* d_in, const int* in_sizes, int n_in,
                              void* d_out, int out_size, void* d_ws, size_t ws_size,
                              hipStream_t stream)
{
    const float* x     = (const float*)d_in[0];
    const float* q_w   = (const float*)d_in[1];
    const float* q_b   = (const float*)d_in[2];
    const float* q_s   = (const float*)d_in[3];
    const float* q_be  = (const float*)d_in[4];
    const float* k_w   = (const float*)d_in[5];
    const float* k_b   = (const float*)d_in[6];
    const float* k_s   = (const float*)d_in[7];
    const float* k_be  = (const float*)d_in[8];
    const float* v_w   = (const float*)d_in[9];
    const float* v_b   = (const float*)d_in[10];
    const float* v_s   = (const float*)d_in[11];
    const float* v_be  = (const float*)d_in[12];
    const float* f_w   = (const float*)d_in[13];
    const float* f_b   = (const float*)d_in[14];
    const float* f_s   = (const float*)d_in[15];
    const float* f_be  = (const float*)d_in[16];

    float* y_out  = (float*)d_out;                        // (8,256,32,32)
    float* am_out = (float*)d_out + (size_t)B_ * C_ * N_; // (8,32,32)

    char* w = (char*)d_ws;
    float* q       = (float*)w;  w += (size_t)B_ * C_ * N_ * 4;      // 8 MB
    float* k       = (float*)w;  w += (size_t)B_ * C_ * N_ * 4;      // 8 MB
    uint4* qpk     = (uint4*)w;  w += (size_t)B_ * NH_ * N_ * 128;   // 8 MB
    uint4* kpk     = (uint4*)w;  w += (size_t)B_ * NH_ * N_ * 128;   // 8 MB
    u16*   vbf     = (u16*)w;    w += (size_t)B_ * C_ * N_ * 2;      // 4 MB
    u16*   aout_bt = (u16*)w;    w += (size_t)B_ * N_ * C_ * 2;      // 4 MB
    float* ampart  = (float*)w;  w += (size_t)B_ * NH_ * 16 * N_ * 4;// 4 MB
    float* amtmp   = (float*)w;  w += (size_t)B_ * 16 * N_ * 4;      // 512 KB
    u16*   wbf     = (u16*)w;                                        // 128 KB

    qkv_kernel<<<(B_ * C_ * N_) / 256, 256, 0, stream>>>(
        x, q_w, q_b, q_s, q_be, k_w, k_b, k_s, k_be,
        v_w, v_b, v_s, v_be, q, k, vbf);

    pack_kernel<<<(B_ * NH_ * N_) / 256, 256, 0, stream>>>(q, k, qpk, kpk);

    wcvt_kernel<<<64, 256, 0, stream>>>(f_w, wbf);

    attn_kernel<<<B_ * NH_ * 16, 256, 0, stream>>>(
        qpk, kpk, vbf, aout_bt, ampart);

    am1_kernel<<<B_ * 16, 256, 0, stream>>>(ampart, amtmp);
    am2_kernel<<<B_, 256, 0, stream>>>(amtmp, am_out);

    fconv_kernel<<<B_ * 32, 256, 0, stream>>>(
        aout_bt, wbf, x, f_s, f_b, f_be, y_out);
}